// Round 1
// baseline (62.746 us; speedup 1.0000x reference)
//
#include <hip/hip_runtime.h>
#include <hip/hip_bf16.h>

#define T_FRAMES 100
#define R_REP    8
#define N_ATOMS  83
#define N_BINS   120

// ---------------- kernel 1: zero the per-replica histograms in ws ----------
__global__ void zero_ws_kernel(unsigned int* __restrict__ ws) {
    int i = blockIdx.x * blockDim.x + threadIdx.x;
    if (i < R_REP * N_BINS) ws[i] = 0u;
}

// ---------------- kernel 2: min-image distances + histogram ----------------
// One block per (frame t, replica r). 800 blocks of 256 threads.
__global__ __launch_bounds__(256) void rdf_hist_kernel(
        const float* __restrict__ radii,   // [T, R, N, 3]
        const float* __restrict__ cell,    // [3, 3]
        const float* __restrict__ bins,    // [N_BINS+1]
        unsigned int* __restrict__ hist_g) // [R, N_BINS]
{
#pragma clang fp contract(off)
    __shared__ float sx[N_ATOMS], sy[N_ATOMS], sz[N_ATOMS];
    __shared__ float sshift[27][3];
    __shared__ float sbins[N_BINS + 1];
    __shared__ unsigned int shist[N_BINS];

    const int tid = threadIdx.x;
    const int blk = blockIdx.x;      // 0..T*R-1
    const int t = blk / R_REP;
    const int r = blk % R_REP;

    // stage this frame's atoms (SoA)
    for (int i = tid; i < N_ATOMS; i += 256) {
        const float* p = radii + (((size_t)t * R_REP + r) * N_ATOMS + i) * 3;
        sx[i] = p[0]; sy[i] = p[1]; sz[i] = p[2];
    }
    for (int i = tid; i <= N_BINS; i += 256) sbins[i] = bins[i];
    for (int i = tid; i < N_BINS; i += 256) shist[i] = 0u;

    // 27 periodic-image shifts: combos({-1,0,1}^3) @ cell, sequential-add order
    if (tid < 27) {
        float fa = (float)(tid % 3 - 1);
        float fb = (float)((tid / 3) % 3 - 1);
        float fc = (float)(tid / 9 - 1);
        for (int d = 0; d < 3; ++d)
            sshift[tid][d] = (fa * cell[0 * 3 + d] + fb * cell[1 * 3 + d]) + fc * cell[2 * 3 + d];
    }
    __syncthreads();

    // hoist shifts into registers (fully unrolled inner loop uses static idx)
    float shx[27], shy[27], shz[27];
#pragma unroll
    for (int k = 0; k < 27; ++k) {
        shx[k] = sshift[k][0];
        shy[k] = sshift[k][1];
        shz[k] = sshift[k][2];
    }

    const float b0   = sbins[0];
    const float bmax = sbins[N_BINS];
    const float inv_step = (float)N_BINS / (bmax - b0);   // guess only; fixed up exactly

    for (int p = tid; p < N_ATOMS * N_ATOMS; p += 256) {
        const int i = p / N_ATOMS;
        const int j = p - i * N_ATOMS;
        const float dx = sx[i] - sx[j];
        const float dy = sy[i] - sy[j];
        const float dz = sz[i] - sz[j];
        float d2m = 3.4e38f;
#pragma unroll
        for (int k = 0; k < 27; ++k) {
            const float t0 = dx - shx[k];
            const float t1 = dy - shy[k];
            const float t2 = dz - shz[k];
            const float d2 = (t0 * t0 + t1 * t1) + t2 * t2;  // contract(off): matches numpy
            d2m = fminf(d2m, d2);
        }
        const float d = sqrtf(d2m);   // IEEE-correct (no fast-math)
        if (d >= b0 && d <= bmax) {
            // initial guess, then exact searchsorted(bins, d, 'right')-1 fixup
            int idx = (int)((d - b0) * inv_step);
            if (idx > N_BINS - 1) idx = N_BINS - 1;
            if (idx < 0) idx = 0;
            while (idx > 0 && d < sbins[idx]) --idx;
            while (idx < N_BINS - 1 && d >= sbins[idx + 1]) ++idx;
            atomicAdd(&shist[idx], 1u);
        }
    }
    __syncthreads();

    for (int i = tid; i < N_BINS; i += 256)
        if (shist[i]) atomicAdd(&hist_g[r * N_BINS + i], shist[i]);
}

// ---------------- kernel 3: rdf = hist / Z, maes ---------------------------
__global__ __launch_bounds__(256) void finalize_kernel(
        const unsigned int* __restrict__ hist_g, // [R, N_BINS]
        const float* __restrict__ cell,
        const float* __restrict__ bins,
        const float* __restrict__ gt,            // [N_BINS]
        float* __restrict__ out)                 // [R*N_BINS + R]
{
    __shared__ float srdf[R_REP * N_BINS];
    const int tid = threadIdx.x;

    const float c0x = cell[0], c0y = cell[1], c0z = cell[2];
    const float c1x = cell[3], c1y = cell[4], c1z = cell[5];
    const float c2x = cell[6], c2y = cell[7], c2z = cell[8];
    const float crx = c0y * c1z - c0z * c1y;
    const float cry = c0z * c1x - c0x * c1z;
    const float crz = c0x * c1y - c0y * c1x;
    const float vol = fabsf(crx * c2x + cry * c2y + crz * c2z);
    const float rho = (float)(T_FRAMES * N_ATOMS * N_ATOMS) / vol;
    const float coef = (rho * 1.33333337f) * 3.14159274f;  // rho * 4/3 * pi, f32 chain

    for (int e = tid; e < R_REP * N_BINS; e += 256) {
        const int b = e % N_BINS;
        const float b1 = bins[b], b2 = bins[b + 1];
        const float Z = coef * (b2 * b2 * b2 - b1 * b1 * b1);
        const float v = (float)hist_g[e] / Z;
        out[e] = v;
        srdf[e] = v;
    }
    __syncthreads();

    if (tid < R_REP) {
        float s = 0.f;
        for (int b = 0; b < N_BINS; ++b)
            s += fabsf(srdf[tid * N_BINS + b] - gt[b]);
        out[R_REP * N_BINS + tid] = 6.0f * (s * (1.0f / (float)N_BINS));
    }
}

extern "C" void kernel_launch(void* const* d_in, const int* in_sizes, int n_in,
                              void* d_out, int out_size, void* d_ws, size_t ws_size,
                              hipStream_t stream) {
    const float* radii = (const float*)d_in[0];  // [100,8,83,3]
    const float* cell  = (const float*)d_in[1];  // [3,3]
    const float* gt    = (const float*)d_in[2];  // [120]
    const float* bins  = (const float*)d_in[3];  // [121]
    float* out = (float*)d_out;                  // 8*120 rdfs + 8 maes
    unsigned int* hist = (unsigned int*)d_ws;    // R*N_BINS u32

    hipLaunchKernelGGL(zero_ws_kernel, dim3((R_REP * N_BINS + 255) / 256), dim3(256), 0, stream, hist);
    hipLaunchKernelGGL(rdf_hist_kernel, dim3(T_FRAMES * R_REP), dim3(256), 0, stream,
                       radii, cell, bins, hist);
    hipLaunchKernelGGL(finalize_kernel, dim3(1), dim3(256), 0, stream,
                       hist, cell, bins, gt, out);
}

// Round 2
// 41.107 us; speedup vs baseline: 1.5264x; 1.5264x over previous
//
#include <hip/hip_runtime.h>
#include <hip/hip_bf16.h>

#define T_FRAMES 100
#define R_REP    8
#define N_ATOMS  83
#define N_BINS   120
#define NPAIRS   (N_ATOMS * (N_ATOMS - 1) / 2)   // 3403
#define BLK      512

__device__ __forceinline__ int rowstart(int i) {
    // upper-triangle (i<j) row start: i*(2N-1-i)/2 with N=83 -> i*(165-i)/2
    return (i * (165 - i)) >> 1;
}

// ---------------- kernel 1: min-image distances + histogram ----------------
// One block per (frame t, replica r). 800 blocks of 512 threads, i<j pairs, weight 2.
__global__ __launch_bounds__(BLK) void rdf_hist_kernel(
        const float* __restrict__ radii,   // [T, R, N, 3]
        const float* __restrict__ cell,    // [3, 3]
        const float* __restrict__ bins,    // [N_BINS+1]
        unsigned int* __restrict__ hist_g) // [R, N_BINS]
{
#pragma clang fp contract(off)
    __shared__ float sx[N_ATOMS], sy[N_ATOMS], sz[N_ATOMS];
    __shared__ float sshift[27][3];
    __shared__ float sbins[N_BINS + 1];
    __shared__ unsigned int shist[N_BINS];

    const int tid = threadIdx.x;
    const int blk = blockIdx.x;      // 0..T*R-1
    const int t = blk / R_REP;
    const int r = blk % R_REP;

    // stage this frame's atoms (SoA)
    for (int i = tid; i < N_ATOMS; i += BLK) {
        const float* p = radii + (((size_t)t * R_REP + r) * N_ATOMS + i) * 3;
        sx[i] = p[0]; sy[i] = p[1]; sz[i] = p[2];
    }
    for (int i = tid; i <= N_BINS; i += BLK) sbins[i] = bins[i];
    for (int i = tid; i < N_BINS; i += BLK) shist[i] = 0u;

    // 27 periodic-image shifts: combos({-1,0,1}^3) @ cell (order irrelevant for min)
    if (tid < 27) {
        float fa = (float)(tid % 3 - 1);
        float fb = (float)((tid / 3) % 3 - 1);
        float fc = (float)(tid / 9 - 1);
        for (int d = 0; d < 3; ++d)
            sshift[tid][d] = (fa * cell[0 * 3 + d] + fb * cell[1 * 3 + d]) + fc * cell[2 * 3 + d];
    }
    __syncthreads();

    float shx[27], shy[27], shz[27];
#pragma unroll
    for (int k = 0; k < 27; ++k) {
        shx[k] = sshift[k][0];
        shy[k] = sshift[k][1];
        shz[k] = sshift[k][2];
    }

    const float b0   = sbins[0];
    const float bmax = sbins[N_BINS];
    const float inv_step = (float)N_BINS / (bmax - b0);   // guess only; fixed up exactly

    for (int p = tid; p < NPAIRS; p += BLK) {
        // invert triangular index: find i s.t. rowstart(i) <= p < rowstart(i+1)
        int i = (int)((165.0f - sqrtf((float)(27225 - 8 * p))) * 0.5f);
        if (i < 0) i = 0;
        if (i > N_ATOMS - 2) i = N_ATOMS - 2;
        while (rowstart(i + 1) <= p) ++i;
        while (rowstart(i) > p) --i;
        const int j = p - rowstart(i) + i + 1;

        const float dx = sx[i] - sx[j];
        const float dy = sy[i] - sy[j];
        const float dz = sz[i] - sz[j];
        float d2m = 3.4e38f;
#pragma unroll
        for (int k = 0; k < 27; ++k) {
            const float t0 = dx - shx[k];
            const float t1 = dy - shy[k];
            const float t2 = dz - shz[k];
            const float d2 = (t0 * t0 + t1 * t1) + t2 * t2;  // contract(off): matches numpy
            d2m = fminf(d2m, d2);
        }
        const float d = sqrtf(d2m);   // IEEE-correct
        if (d >= b0 && d <= bmax) {
            int idx = (int)((d - b0) * inv_step);
            if (idx > N_BINS - 1) idx = N_BINS - 1;
            if (idx < 0) idx = 0;
            while (idx > 0 && d < sbins[idx]) --idx;
            while (idx < N_BINS - 1 && d >= sbins[idx + 1]) ++idx;
            atomicAdd(&shist[idx], 2u);   // (i,j) and (j,i) are bit-identical
        }
    }
    __syncthreads();

    for (int i = tid; i < N_BINS; i += BLK)
        if (shist[i]) atomicAdd(&hist_g[r * N_BINS + i], shist[i]);
}

// ---------------- kernel 2: rdf = hist / Z, maes ---------------------------
__global__ __launch_bounds__(256) void finalize_kernel(
        const unsigned int* __restrict__ hist_g, // [R, N_BINS]
        const float* __restrict__ cell,
        const float* __restrict__ bins,
        const float* __restrict__ gt,            // [N_BINS]
        float* __restrict__ out)                 // [R*N_BINS + R]
{
    __shared__ float srdf[R_REP * N_BINS];
    const int tid = threadIdx.x;

    const float c0x = cell[0], c0y = cell[1], c0z = cell[2];
    const float c1x = cell[3], c1y = cell[4], c1z = cell[5];
    const float c2x = cell[6], c2y = cell[7], c2z = cell[8];
    const float crx = c0y * c1z - c0z * c1y;
    const float cry = c0z * c1x - c0x * c1z;
    const float crz = c0x * c1y - c0y * c1x;
    const float vol = fabsf(crx * c2x + cry * c2y + crz * c2z);
    const float rho = (float)(T_FRAMES * N_ATOMS * N_ATOMS) / vol;
    const float coef = (rho * 1.33333337f) * 3.14159274f;  // rho * 4/3 * pi, f32 chain

    for (int e = tid; e < R_REP * N_BINS; e += 256) {
        const int b = e % N_BINS;
        const float b1 = bins[b], b2 = bins[b + 1];
        const float Z = coef * (b2 * b2 * b2 - b1 * b1 * b1);
        const float v = (float)hist_g[e] / Z;
        out[e] = v;
        srdf[e] = v;
    }
    __syncthreads();

    if (tid < R_REP) {
        float s = 0.f;
        for (int b = 0; b < N_BINS; ++b)
            s += fabsf(srdf[tid * N_BINS + b] - gt[b]);
        out[R_REP * N_BINS + tid] = 6.0f * (s * (1.0f / (float)N_BINS));
    }
}

extern "C" void kernel_launch(void* const* d_in, const int* in_sizes, int n_in,
                              void* d_out, int out_size, void* d_ws, size_t ws_size,
                              hipStream_t stream) {
    const float* radii = (const float*)d_in[0];  // [100,8,83,3]
    const float* cell  = (const float*)d_in[1];  // [3,3]
    const float* gt    = (const float*)d_in[2];  // [120]
    const float* bins  = (const float*)d_in[3];  // [121]
    float* out = (float*)d_out;                  // 8*120 rdfs + 8 maes
    unsigned int* hist = (unsigned int*)d_ws;    // R*N_BINS u32

    hipMemsetAsync(hist, 0, R_REP * N_BINS * sizeof(unsigned int), stream);
    hipLaunchKernelGGL(rdf_hist_kernel, dim3(T_FRAMES * R_REP), dim3(BLK), 0, stream,
                       radii, cell, bins, hist);
    hipLaunchKernelGGL(finalize_kernel, dim3(1), dim3(256), 0, stream,
                       hist, cell, bins, gt, out);
}

// Round 3
// 38.343 us; speedup vs baseline: 1.6364x; 1.0721x over previous
//
#include <hip/hip_runtime.h>
#include <hip/hip_bf16.h>

#define T_FRAMES 100
#define R_REP    8
#define N_ATOMS  83
#define N_BINS   120
#define NPAIRS   (N_ATOMS * (N_ATOMS - 1) / 2)   // 3403
#define BLK      256
#define PPT      7          // pairs per thread: 256*7=1792 >= ceil(3403/2)
#define HALF0    1702       // pairs in block-half 0 (half 1 gets 1701)

__device__ __forceinline__ int rowstart(int i) {
    // upper-triangle (i<j) row start for N=83: i*(165-i)/2
    return (i * (165 - i)) >> 1;
}

// ---------------- kernel 1: min-image distances + histogram ----------------
// Two blocks per (frame t, replica r); each handles ~1702 of the 3403 i<j pairs.
__global__ __launch_bounds__(BLK) void rdf_hist_kernel(
        const float* __restrict__ radii,   // [T, R, N, 3]
        const float* __restrict__ cell,    // [3, 3]
        const float* __restrict__ bins,    // [N_BINS+1]
        unsigned int* __restrict__ hist_g) // [R, N_BINS]
{
#pragma clang fp contract(off)
    __shared__ float sx[N_ATOMS], sy[N_ATOMS], sz[N_ATOMS];
    __shared__ float sshift[27][4];        // stride 16B -> aligned vector reads
    __shared__ float sbins[N_BINS + 1];
    __shared__ unsigned int shist[N_BINS];

    const int tid  = threadIdx.x;
    const int blk  = blockIdx.x;           // 0 .. 2*T*R-1
    const int fr   = blk >> 1;             // frame index 0..799
    const int half = blk & 1;
    const int t = fr / R_REP;
    const int r = fr % R_REP;
    const int pstart = half ? HALF0 : 0;
    const int pcount = half ? (NPAIRS - HALF0) : HALF0;

    // stage this frame's atoms (SoA)
    for (int i = tid; i < N_ATOMS; i += BLK) {
        const float* p = radii + (((size_t)t * R_REP + r) * N_ATOMS + i) * 3;
        sx[i] = p[0]; sy[i] = p[1]; sz[i] = p[2];
    }
    for (int i = tid; i <= N_BINS; i += BLK) sbins[i] = bins[i];
    for (int i = tid; i < N_BINS; i += BLK) shist[i] = 0u;

    // 27 periodic-image shifts: combos({-1,0,1}^3) @ cell (fp32 chain as numpy)
    if (tid < 27) {
        float fa = (float)(tid % 3 - 1);
        float fb = (float)((tid / 3) % 3 - 1);
        float fc = (float)(tid / 9 - 1);
        for (int d = 0; d < 3; ++d)
            sshift[tid][d] = (fa * cell[0 * 3 + d] + fb * cell[1 * 3 + d]) + fc * cell[2 * 3 + d];
    }
    __syncthreads();

    // ---- load phase: resolve PPT pairs per thread into registers ----------
    float dx[PPT], dy[PPT], dz[PPT], d2m[PPT];
#pragma unroll
    for (int s = 0; s < PPT; ++s) {
        const int l = tid + s * BLK;               // local pair idx in this half
        const int p = (l < pcount) ? (pstart + l) : 0;   // clamp tail to pair 0
        int i = (int)((165.0f - sqrtf((float)(27225 - 8 * p))) * 0.5f);
        if (i < 0) i = 0;
        if (i > N_ATOMS - 2) i = N_ATOMS - 2;
        while (rowstart(i + 1) <= p) ++i;
        while (rowstart(i) > p) --i;
        const int j = p - rowstart(i) + i + 1;
        dx[s] = sx[i] - sx[j];
        dy[s] = sy[i] - sy[j];
        dz[s] = sz[i] - sz[j];
        d2m[s] = 3.4e38f;
    }

    // ---- shift loop outermost: 1 broadcast LDS read per k, 7 pairs amortize
    for (int k = 0; k < 27; ++k) {
        const float hx = sshift[k][0];
        const float hy = sshift[k][1];
        const float hz = sshift[k][2];
#pragma unroll
        for (int s = 0; s < PPT; ++s) {
            const float t0 = dx[s] - hx;
            const float t1 = dy[s] - hy;
            const float t2 = dz[s] - hz;
            const float d2 = (t0 * t0 + t1 * t1) + t2 * t2;  // contract off
            d2m[s] = fminf(d2m[s], d2);
        }
    }

    // ---- binning phase -----------------------------------------------------
    const float b0   = sbins[0];
    const float bmax = sbins[N_BINS];
    const float inv_step = (float)N_BINS / (bmax - b0);
#pragma unroll
    for (int s = 0; s < PPT; ++s) {
        const int l = tid + s * BLK;
        if (l >= pcount) continue;
        const float d = sqrtf(d2m[s]);             // IEEE-correct
        if (d >= b0 && d <= bmax) {
            int idx = (int)((d - b0) * inv_step);
            if (idx > N_BINS - 1) idx = N_BINS - 1;
            if (idx < 0) idx = 0;
            while (idx > 0 && d < sbins[idx]) --idx;
            while (idx < N_BINS - 1 && d >= sbins[idx + 1]) ++idx;
            atomicAdd(&shist[idx], 2u);            // (i,j)/(j,i) bit-identical
        }
    }
    __syncthreads();

    for (int i = tid; i < N_BINS; i += BLK)
        if (shist[i]) atomicAdd(&hist_g[r * N_BINS + i], shist[i]);
}

// ---------------- kernel 2: rdf = hist / Z, maes ---------------------------
__global__ __launch_bounds__(256) void finalize_kernel(
        const unsigned int* __restrict__ hist_g, // [R, N_BINS]
        const float* __restrict__ cell,
        const float* __restrict__ bins,
        const float* __restrict__ gt,            // [N_BINS]
        float* __restrict__ out)                 // [R*N_BINS + R]
{
    __shared__ float srdf[R_REP * N_BINS];
    const int tid = threadIdx.x;

    const float c0x = cell[0], c0y = cell[1], c0z = cell[2];
    const float c1x = cell[3], c1y = cell[4], c1z = cell[5];
    const float c2x = cell[6], c2y = cell[7], c2z = cell[8];
    const float crx = c0y * c1z - c0z * c1y;
    const float cry = c0z * c1x - c0x * c1z;
    const float crz = c0x * c1y - c0y * c1x;
    const float vol = fabsf(crx * c2x + cry * c2y + crz * c2z);
    const float rho = (float)(T_FRAMES * N_ATOMS * N_ATOMS) / vol;
    const float coef = (rho * 1.33333337f) * 3.14159274f;  // rho * 4/3 * pi

    for (int e = tid; e < R_REP * N_BINS; e += 256) {
        const int b = e % N_BINS;
        const float b1 = bins[b], b2 = bins[b + 1];
        const float Z = coef * (b2 * b2 * b2 - b1 * b1 * b1);
        const float v = (float)hist_g[e] / Z;
        out[e] = v;
        srdf[e] = v;
    }
    __syncthreads();

    if (tid < R_REP) {
        float s = 0.f;
        for (int b = 0; b < N_BINS; ++b)
            s += fabsf(srdf[tid * N_BINS + b] - gt[b]);
        out[R_REP * N_BINS + tid] = 6.0f * (s * (1.0f / (float)N_BINS));
    }
}

extern "C" void kernel_launch(void* const* d_in, const int* in_sizes, int n_in,
                              void* d_out, int out_size, void* d_ws, size_t ws_size,
                              hipStream_t stream) {
    const float* radii = (const float*)d_in[0];  // [100,8,83,3]
    const float* cell  = (const float*)d_in[1];  // [3,3]
    const float* gt    = (const float*)d_in[2];  // [120]
    const float* bins  = (const float*)d_in[3];  // [121]
    float* out = (float*)d_out;                  // 8*120 rdfs + 8 maes
    unsigned int* hist = (unsigned int*)d_ws;    // R*N_BINS u32

    hipMemsetAsync(hist, 0, R_REP * N_BINS * sizeof(unsigned int), stream);
    hipLaunchKernelGGL(rdf_hist_kernel, dim3(2 * T_FRAMES * R_REP), dim3(BLK), 0, stream,
                       radii, cell, bins, hist);
    hipLaunchKernelGGL(finalize_kernel, dim3(1), dim3(256), 0, stream,
                       hist, cell, bins, gt, out);
}